// Round 1
// baseline (607.172 us; speedup 1.0000x reference)
//
#include <hip/hip_runtime.h>
#include <math.h>

#define H 96
#define W 96
#define HW 9216
#define B 8
#define CIN 256
#define CM 64
#define NPOS (B*HW)   /* 73728 */

/* workspace layout (float offsets) */
#define OFF_W1T   0         /* 16384  : w1t[c*64+o]            */
#define OFF_WOFFT 16384     /* 10368  : wofft[c*162+o*9+k]     */
#define OFF_WDT   26752     /* 36864  : wdt[(c*9+k)*64+o]      */
#define OFF_W2T   63616     /* 16384  : w2t[c*256+o]           */
#define OFF_BNS   80000     /* 64     : gamma/sqrt(var+eps)    */
#define OFF_BNB   80064     /* 64     : beta - rmean*scale     */
#define OFF_FEAT  81920     /* 4718592: feat[b][c][hw]         */
#define OFF_OFFS  4800512   /* 1327104: offs[b][18][hw]        */
#define OFF_V     6127616   /* 4718592: v[b][c][hw]            */
/* total 10846208 floats = 41.4 MiB of d_ws */

__global__ __launch_bounds__(256) void k0_prep(
    const float* __restrict__ w1, const float* __restrict__ woff,
    const float* __restrict__ wd, const float* __restrict__ w2,
    const float* __restrict__ gamma, const float* __restrict__ beta,
    const float* __restrict__ rmean, const float* __restrict__ rvar,
    float* __restrict__ ws) {
  int i = blockIdx.x * 256 + threadIdx.x;
  if (i < 16384) {                      /* w1 [o][c] -> w1t [c][o] */
    int c = i >> 6, o = i & 63;
    ws[OFF_W1T + i] = w1[o * CIN + c];
  } else if (i < 26752) {               /* woff [o][c][k] -> wofft [c][o*9+k] */
    int j = i - 16384;
    int c = j / 162, r = j - c * 162;
    int o = r / 9, k = r - o * 9;
    ws[OFF_WOFFT + j] = woff[(o * 64 + c) * 9 + k];
  } else if (i < 63616) {               /* wd [o][c][k] -> wdt [(c*9+k)][o] */
    int j = i - 26752;
    int o = j & 63, ck = j >> 6;
    int c = ck / 9, k = ck - c * 9;
    ws[OFF_WDT + j] = wd[(o * 64 + c) * 9 + k];
  } else if (i < 80000) {               /* w2 [o][c] -> w2t [c][o] */
    int j = i - 63616;
    int c = j >> 8, o = j & 255;
    ws[OFF_W2T + j] = w2[o * 64 + c];
  } else if (i < 80064) {               /* BN folding */
    int o = i - 80000;
    float inv = gamma[o] / sqrtf(rvar[o] + 1e-5f);
    ws[OFF_BNS + o] = inv;
    ws[OFF_BNB + o] = beta[o] - rmean[o] * inv;
  }
}

/* pwconv1: feat[b,o,hw] = sum_c x[b,c,hw]*w1[o,c] + b1[o] */
__global__ __launch_bounds__(256) void k1_pw1(
    const float* __restrict__ x, const float* __restrict__ w1t,
    const float* __restrict__ b1, float* __restrict__ feat) {
  int g = blockIdx.x * 256 + threadIdx.x;
  int b = g / HW, hw = g - b * HW;
  const float* xb = x + b * CIN * HW + hw;
  float acc[CM];
#pragma unroll
  for (int o = 0; o < CM; o++) acc[o] = 0.f;
  for (int c = 0; c < CIN; c++) {
    float xv = xb[c * HW];
    const float4* wr = (const float4*)(w1t + c * CM);  /* wave-uniform addr */
#pragma unroll
    for (int o4 = 0; o4 < CM / 4; o4++) {
      float4 wv = wr[o4];
      acc[4 * o4 + 0] += xv * wv.x;
      acc[4 * o4 + 1] += xv * wv.y;
      acc[4 * o4 + 2] += xv * wv.z;
      acc[4 * o4 + 3] += xv * wv.w;
    }
  }
  float* fb = feat + b * CM * HW + hw;
#pragma unroll
  for (int o = 0; o < CM; o++) fb[o * HW] = acc[o] + b1[o];
}

/* offset conv: 3x3 SAME, 64 -> 18 channels */
__global__ __launch_bounds__(256) void k2_off(
    const float* __restrict__ feat, const float* __restrict__ wofft,
    const float* __restrict__ boff, float* __restrict__ offs) {
  int g = blockIdx.x * 256 + threadIdx.x;
  int b = g / HW, hw = g - b * HW;
  int i = hw / W, j = hw - i * W;
  int idx9[9];
  float m9[9];
#pragma unroll
  for (int kh = 0; kh < 3; kh++) {
#pragma unroll
    for (int kw = 0; kw < 3; kw++) {
      int yy = i + kh - 1, xx = j + kw - 1;
      bool ok = (yy >= 0) && (yy < H) && (xx >= 0) && (xx < W);
      idx9[kh * 3 + kw] = ok ? yy * W + xx : 0;
      m9[kh * 3 + kw] = ok ? 1.f : 0.f;
    }
  }
  const float* fb = feat + b * CM * HW;
  float acc[18];
#pragma unroll
  for (int o = 0; o < 18; o++) acc[o] = 0.f;
  for (int c = 0; c < CM; c++) {
    const float* fc = fb + c * HW;
    float v[9];
#pragma unroll
    for (int k = 0; k < 9; k++) v[k] = fc[idx9[k]] * m9[k];
    const float* wr = wofft + c * 162;  /* wave-uniform */
#pragma unroll
    for (int o = 0; o < 18; o++)
#pragma unroll
      for (int k = 0; k < 9; k++)
        acc[o] += v[k] * wr[o * 9 + k];
  }
  float* ob = offs + b * 18 * HW + hw;
#pragma unroll
  for (int o = 0; o < 18; o++) ob[o * HW] = acc[o] + boff[o];
}

/* deformable conv + fused BN */
__global__ __launch_bounds__(256) void k3_deform(
    const float* __restrict__ feat, const float* __restrict__ offs,
    const float* __restrict__ wdt, const float* __restrict__ bd,
    const float* __restrict__ bns, const float* __restrict__ bnb,
    float* __restrict__ v) {
  int g = blockIdx.x * 256 + threadIdx.x;
  int b = g / HW, hw = g - b * HW;
  int i = hw / W, j = hw - i * W;
  const float* fb = feat + b * CM * HW;
  const float* ob = offs + b * 18 * HW + hw;
  float acc[CM];
#pragma unroll
  for (int o = 0; o < CM; o++) acc[o] = 0.f;
  for (int k = 0; k < 9; k++) {
    float dy = ob[(2 * k + 0) * HW];
    float dx = ob[(2 * k + 1) * HW];
    float py = (float)(i + k / 3 - 1) + dy;
    float px = (float)(j + k % 3 - 1) + dx;
    float y0f = floorf(py), x0f = floorf(px);
    int y0 = (int)y0f, x0 = (int)x0f;
    float fy = py - y0f, fx = px - x0f;
    float w00 = (1.f - fy) * (1.f - fx), w01 = (1.f - fy) * fx;
    float w10 = fy * (1.f - fx), w11 = fy * fx;
    bool vy0 = (y0 >= 0) && (y0 < H), vy1 = (y0 + 1 >= 0) && (y0 + 1 < H);
    bool vx0 = (x0 >= 0) && (x0 < W), vx1 = (x0 + 1 >= 0) && (x0 + 1 < W);
    if (!(vy0 && vx0)) w00 = 0.f;
    if (!(vy0 && vx1)) w01 = 0.f;
    if (!(vy1 && vx0)) w10 = 0.f;
    if (!(vy1 && vx1)) w11 = 0.f;
    int yi0 = min(max(y0, 0), H - 1), yi1 = min(max(y0 + 1, 0), H - 1);
    int xi0 = min(max(x0, 0), W - 1), xi1 = min(max(x0 + 1, 0), W - 1);
    int i00 = yi0 * W + xi0, i01 = yi0 * W + xi1;
    int i10 = yi1 * W + xi0, i11 = yi1 * W + xi1;
    for (int c = 0; c < CM; c++) {
      const float* fc = fb + c * HW;
      float s = w00 * fc[i00] + w01 * fc[i01] + w10 * fc[i10] + w11 * fc[i11];
      const float4* wr = (const float4*)(wdt + (c * 9 + k) * 64); /* uniform */
#pragma unroll
      for (int o4 = 0; o4 < 16; o4++) {
        float4 wv = wr[o4];
        acc[4 * o4 + 0] += s * wv.x;
        acc[4 * o4 + 1] += s * wv.y;
        acc[4 * o4 + 2] += s * wv.z;
        acc[4 * o4 + 3] += s * wv.w;
      }
    }
  }
  float* vb = v + b * CM * HW + hw;
#pragma unroll
  for (int o = 0; o < CM; o++)
    vb[o * HW] = (acc[o] + bd[o]) * bns[o] + bnb[o];
}

/* pwconv2 (64->256) + sigmoid gate; grid.y = output-channel quadrant */
__global__ __launch_bounds__(256) void k4_pw2(
    const float* __restrict__ x, const float* __restrict__ v,
    const float* __restrict__ w2t, const float* __restrict__ b2,
    float* __restrict__ out) {
  int g = blockIdx.x * 256 + threadIdx.x;
  int q = blockIdx.y;
  int b = g / HW, hw = g - b * HW;
  const float* vb = v + b * CM * HW + hw;
  float acc[64];
#pragma unroll
  for (int o = 0; o < 64; o++) acc[o] = 0.f;
  for (int c = 0; c < CM; c++) {
    float vv = vb[c * HW];
    const float4* wr = (const float4*)(w2t + c * 256 + q * 64); /* uniform */
#pragma unroll
    for (int o4 = 0; o4 < 16; o4++) {
      float4 wv = wr[o4];
      acc[4 * o4 + 0] += vv * wv.x;
      acc[4 * o4 + 1] += vv * wv.y;
      acc[4 * o4 + 2] += vv * wv.z;
      acc[4 * o4 + 3] += vv * wv.w;
    }
  }
  const float* xb = x + (b * CIN + q * 64) * HW + hw;
  float* outb = out + (b * CIN + q * 64) * HW + hw;
#pragma unroll
  for (int o = 0; o < 64; o++) {
    float val = acc[o] + b2[q * 64 + o];
    float sg = 1.f / (1.f + __expf(-val));
    outb[o * HW] = xb[o * HW] * sg;
  }
}

extern "C" void kernel_launch(void* const* d_in, const int* in_sizes, int n_in,
                              void* d_out, int out_size, void* d_ws, size_t ws_size,
                              hipStream_t stream) {
  const float* x     = (const float*)d_in[0];
  const float* w1    = (const float*)d_in[1];
  const float* b1    = (const float*)d_in[2];
  const float* woff  = (const float*)d_in[3];
  const float* boff  = (const float*)d_in[4];
  const float* wd    = (const float*)d_in[5];
  const float* bd    = (const float*)d_in[6];
  const float* gamma = (const float*)d_in[7];
  const float* beta  = (const float*)d_in[8];
  const float* rmean = (const float*)d_in[9];
  const float* rvar  = (const float*)d_in[10];
  const float* w2    = (const float*)d_in[11];
  const float* b2    = (const float*)d_in[12];
  float* out = (float*)d_out;
  float* ws  = (float*)d_ws;

  dim3 blk(256);
  k0_prep<<<dim3(313), blk, 0, stream>>>(w1, woff, wd, w2, gamma, beta, rmean, rvar, ws);
  k1_pw1<<<dim3(NPOS / 256), blk, 0, stream>>>(x, ws + OFF_W1T, b1, ws + OFF_FEAT);
  k2_off<<<dim3(NPOS / 256), blk, 0, stream>>>(ws + OFF_FEAT, ws + OFF_WOFFT, boff, ws + OFF_OFFS);
  k3_deform<<<dim3(NPOS / 256), blk, 0, stream>>>(ws + OFF_FEAT, ws + OFF_OFFS, ws + OFF_WDT,
                                                  bd, ws + OFF_BNS, ws + OFF_BNB, ws + OFF_V);
  k4_pw2<<<dim3(NPOS / 256, 4), blk, 0, stream>>>(x, ws + OFF_V, ws + OFF_W2T, b2, out);
}

// Round 2
// 438.983 us; speedup vs baseline: 1.3831x; 1.3831x over previous
//
#include <hip/hip_runtime.h>
#include <math.h>

#define H 96
#define W 96
#define HW 9216
#define B 8
#define CIN 256
#define CM 64
#define NPOS (B*HW)   /* 73728 */
#define NBLK (NPOS/64) /* 1152 */

/* workspace layout (float offsets) */
#define OFF_W1T   0         /* 16384  : w1t[c*64+o]            */
#define OFF_WOFFT 16384     /* 10368  : wofft[c*162+o*9+k]     */
#define OFF_WDT   26752     /* 36864  : wdt2[(k*64+c)*64+o]    */
#define OFF_W2T   63616     /* 16384  : w2t[c*256+o]           */
#define OFF_BNS   80000     /* 64     : gamma/sqrt(var+eps)    */
#define OFF_BNB   80064     /* 64     : beta - rmean*scale     */
#define OFF_FEAT  81920     /* 4718592: feat[b][c][hw]         */
#define OFF_OFFS  4800512   /* 1327104: offs[b][18][hw]        */
#define OFF_V     6127616   /* 4718592: v[b][c][hw]            */

__global__ __launch_bounds__(256) void k0_prep(
    const float* __restrict__ w1, const float* __restrict__ woff,
    const float* __restrict__ wd, const float* __restrict__ w2,
    const float* __restrict__ gamma, const float* __restrict__ beta,
    const float* __restrict__ rmean, const float* __restrict__ rvar,
    float* __restrict__ ws) {
  int i = blockIdx.x * 256 + threadIdx.x;
  if (i < 16384) {                      /* w1 [o][c] -> w1t [c][o] */
    int c = i >> 6, o = i & 63;
    ws[OFF_W1T + i] = w1[o * CIN + c];
  } else if (i < 26752) {               /* woff [o][c][k] -> wofft [c][o*9+k] */
    int j = i - 16384;
    int c = j / 162, r = j - c * 162;
    int o = r / 9, k = r - o * 9;
    ws[OFF_WOFFT + j] = woff[(o * 64 + c) * 9 + k];
  } else if (i < 63616) {               /* wd [o][c][k] -> wdt2 [k][c][o] */
    int j = i - 26752;
    int o = j & 63, kc = j >> 6;
    int k = kc >> 6, c = kc & 63;
    ws[OFF_WDT + j] = wd[(o * 64 + c) * 9 + k];
  } else if (i < 80000) {               /* w2 [o][c] -> w2t [c][o] */
    int j = i - 63616;
    int c = j >> 8, o = j & 255;
    ws[OFF_W2T + j] = w2[o * 64 + c];
  } else if (i < 80064) {               /* BN folding */
    int o = i - 80000;
    float inv = gamma[o] / sqrtf(rvar[o] + 1e-5f);
    ws[OFF_BNS + o] = inv;
    ws[OFF_BNB + o] = beta[o] - rmean[o] * inv;
  }
}

/* pwconv1: block = 64 pos, 4 wave-groups x 16 out channels; x staged via LDS */
__global__ __launch_bounds__(256) void k1_pw1(
    const float* __restrict__ x, const float* __restrict__ w1t,
    const float* __restrict__ b1, float* __restrict__ feat) {
  __shared__ float xs[64 * 64];
  int t = threadIdx.x;
  int pos = t & 63;
  int qq = __builtin_amdgcn_readfirstlane(t >> 6);
  int gpos0 = blockIdx.x * 64;
  int b = gpos0 / HW, hw0 = gpos0 - b * HW;
  const float* xb = x + b * CIN * HW + hw0;
  float acc[16];
#pragma unroll
  for (int o = 0; o < 16; o++) acc[o] = 0.f;
  for (int c0 = 0; c0 < CIN; c0 += 64) {
#pragma unroll
    for (int cc = 0; cc < 16; cc++) {
      int ci = qq * 16 + cc;
      xs[ci * 64 + pos] = xb[(c0 + ci) * HW + pos];
    }
    __syncthreads();
#pragma unroll 4
    for (int ci = 0; ci < 64; ci++) {
      float xv = xs[ci * 64 + pos];
      const float4* wr = (const float4*)(w1t + (c0 + ci) * CM + qq * 16);
#pragma unroll
      for (int o4 = 0; o4 < 4; o4++) {
        float4 wv = wr[o4];
        acc[4 * o4 + 0] += xv * wv.x;
        acc[4 * o4 + 1] += xv * wv.y;
        acc[4 * o4 + 2] += xv * wv.z;
        acc[4 * o4 + 3] += xv * wv.w;
      }
    }
    __syncthreads();
  }
  float* fb = feat + b * CM * HW + hw0 + pos;
#pragma unroll
  for (int oo = 0; oo < 16; oo++) {
    int o = qq * 16 + oo;
    fb[o * HW] = acc[oo] + b1[o];
  }
}

/* offset conv 64->18: input channels split 4-way, LDS partial reduce */
__global__ __launch_bounds__(256) void k2_off(
    const float* __restrict__ feat, const float* __restrict__ wofft,
    const float* __restrict__ boff, float* __restrict__ offs) {
  __shared__ float part[4 * 18 * 64];
  int t = threadIdx.x;
  int pos = t & 63;
  int gg = __builtin_amdgcn_readfirstlane(t >> 6);
  int gpos0 = blockIdx.x * 64;
  int b = gpos0 / HW, hw0 = gpos0 - b * HW;
  int hw = hw0 + pos;
  int i = hw / W, j = hw - i * W;
  int idx9[9];
  float m9[9];
#pragma unroll
  for (int kh = 0; kh < 3; kh++)
#pragma unroll
    for (int kw = 0; kw < 3; kw++) {
      int yy = i + kh - 1, xx = j + kw - 1;
      bool ok = (yy >= 0) && (yy < H) && (xx >= 0) && (xx < W);
      idx9[kh * 3 + kw] = ok ? yy * W + xx : 0;
      m9[kh * 3 + kw] = ok ? 1.f : 0.f;
    }
  const float* fb = feat + b * CM * HW;
  float acc[18];
#pragma unroll
  for (int o = 0; o < 18; o++) acc[o] = 0.f;
  for (int cc = 0; cc < 16; cc++) {
    int c = gg * 16 + cc;
    const float* fc = fb + c * HW;
    float v[9];
#pragma unroll
    for (int k = 0; k < 9; k++) v[k] = fc[idx9[k]] * m9[k];
    const float* wr = wofft + c * 162;
#pragma unroll
    for (int o = 0; o < 18; o++)
#pragma unroll
      for (int k = 0; k < 9; k++)
        acc[o] += v[k] * wr[o * 9 + k];
  }
#pragma unroll
  for (int o = 0; o < 18; o++) part[(gg * 18 + o) * 64 + pos] = acc[o];
  __syncthreads();
  for (int r = t; r < 18 * 64; r += 256) {
    int o = r >> 6, p = r & 63;
    float s = part[o * 64 + p] + part[(18 + o) * 64 + p] +
              part[(36 + o) * 64 + p] + part[(54 + o) * 64 + p] + boff[o];
    offs[b * 18 * HW + o * HW + hw0 + p] = s;
  }
}

/* deformable conv + BN: bilinear samples shared across wave-groups via LDS */
__global__ __launch_bounds__(256) void k3_deform(
    const float* __restrict__ feat, const float* __restrict__ offs,
    const float* __restrict__ wdt2, const float* __restrict__ bd,
    const float* __restrict__ bns, const float* __restrict__ bnb,
    float* __restrict__ v) {
  __shared__ float s_lds[64 * 64];
  int t = threadIdx.x;
  int pos = t & 63;
  int qq = __builtin_amdgcn_readfirstlane(t >> 6);
  int gpos0 = blockIdx.x * 64;
  int b = gpos0 / HW, hw0 = gpos0 - b * HW;
  int hw = hw0 + pos;
  int i = hw / W, j = hw - i * W;
  const float* fb = feat + b * CM * HW;
  const float* ob = offs + b * 18 * HW + hw;
  float acc[16];
#pragma unroll
  for (int o = 0; o < 16; o++) acc[o] = 0.f;
  for (int k = 0; k < 9; k++) {
    float dy = ob[(2 * k + 0) * HW];
    float dx = ob[(2 * k + 1) * HW];
    float py = (float)(i + k / 3 - 1) + dy;
    float px = (float)(j + k % 3 - 1) + dx;
    float y0f = floorf(py), x0f = floorf(px);
    int y0 = (int)y0f, x0 = (int)x0f;
    float fy = py - y0f, fx = px - x0f;
    float w00 = (1.f - fy) * (1.f - fx), w01 = (1.f - fy) * fx;
    float w10 = fy * (1.f - fx), w11 = fy * fx;
    bool vy0 = (y0 >= 0) && (y0 < H), vy1 = (y0 + 1 >= 0) && (y0 + 1 < H);
    bool vx0 = (x0 >= 0) && (x0 < W), vx1 = (x0 + 1 >= 0) && (x0 + 1 < W);
    if (!(vy0 && vx0)) w00 = 0.f;
    if (!(vy0 && vx1)) w01 = 0.f;
    if (!(vy1 && vx0)) w10 = 0.f;
    if (!(vy1 && vx1)) w11 = 0.f;
    int yi0 = min(max(y0, 0), H - 1), yi1 = min(max(y0 + 1, 0), H - 1);
    int xi0 = min(max(x0, 0), W - 1), xi1 = min(max(x0 + 1, 0), W - 1);
    int i00 = yi0 * W + xi0, i01 = yi0 * W + xi1;
    int i10 = yi1 * W + xi0, i11 = yi1 * W + xi1;
    /* fill: each wave-group samples its 16 channels */
#pragma unroll
    for (int cc = 0; cc < 16; cc++) {
      int c = qq * 16 + cc;
      const float* fc = fb + c * HW;
      s_lds[c * 64 + pos] =
          w00 * fc[i00] + w01 * fc[i01] + w10 * fc[i10] + w11 * fc[i11];
    }
    __syncthreads();
    const float* wk = wdt2 + k * 64 * 64 + qq * 16;
#pragma unroll 4
    for (int c = 0; c < 64; c++) {
      float s = s_lds[c * 64 + pos];
      const float4* wr = (const float4*)(wk + c * 64);
#pragma unroll
      for (int o4 = 0; o4 < 4; o4++) {
        float4 wv = wr[o4];
        acc[4 * o4 + 0] += s * wv.x;
        acc[4 * o4 + 1] += s * wv.y;
        acc[4 * o4 + 2] += s * wv.z;
        acc[4 * o4 + 3] += s * wv.w;
      }
    }
    __syncthreads();
  }
  float* vb = v + b * CM * HW + hw;
#pragma unroll
  for (int oo = 0; oo < 16; oo++) {
    int o = qq * 16 + oo;
    vb[o * HW] = (acc[oo] + bd[o]) * bns[o] + bnb[o];
  }
}

/* pwconv2 (64->256) + sigmoid gate; v staged once in LDS, 64 out/group */
__global__ __launch_bounds__(256) void k4_pw2(
    const float* __restrict__ x, const float* __restrict__ v,
    const float* __restrict__ w2t, const float* __restrict__ b2,
    float* __restrict__ out) {
  __shared__ float vs[64 * 64];
  int t = threadIdx.x;
  int pos = t & 63;
  int qq = __builtin_amdgcn_readfirstlane(t >> 6);
  int gpos0 = blockIdx.x * 64;
  int b = gpos0 / HW, hw0 = gpos0 - b * HW;
  int hw = hw0 + pos;
  const float* vb = v + b * CM * HW + hw0;
#pragma unroll
  for (int cc = 0; cc < 16; cc++) {
    int ci = qq * 16 + cc;
    vs[ci * 64 + pos] = vb[ci * HW + pos];
  }
  __syncthreads();
  float acc[64];
#pragma unroll
  for (int o = 0; o < 64; o++) acc[o] = 0.f;
#pragma unroll 2
  for (int c = 0; c < CM; c++) {
    float vv = vs[c * 64 + pos];
    const float4* wr = (const float4*)(w2t + c * 256 + qq * 64);
#pragma unroll
    for (int o4 = 0; o4 < 16; o4++) {
      float4 wv = wr[o4];
      acc[4 * o4 + 0] += vv * wv.x;
      acc[4 * o4 + 1] += vv * wv.y;
      acc[4 * o4 + 2] += vv * wv.z;
      acc[4 * o4 + 3] += vv * wv.w;
    }
  }
  const float* xb = x + (b * CIN + qq * 64) * HW + hw;
  float* outb = out + (b * CIN + qq * 64) * HW + hw;
#pragma unroll
  for (int o = 0; o < 64; o++) {
    float val = acc[o] + b2[qq * 64 + o];
    float sg = 1.f / (1.f + __expf(-val));
    outb[o * HW] = xb[o * HW] * sg;
  }
}

extern "C" void kernel_launch(void* const* d_in, const int* in_sizes, int n_in,
                              void* d_out, int out_size, void* d_ws, size_t ws_size,
                              hipStream_t stream) {
  const float* x     = (const float*)d_in[0];
  const float* w1    = (const float*)d_in[1];
  const float* b1    = (const float*)d_in[2];
  const float* woff  = (const float*)d_in[3];
  const float* boff  = (const float*)d_in[4];
  const float* wd    = (const float*)d_in[5];
  const float* bd    = (const float*)d_in[6];
  const float* gamma = (const float*)d_in[7];
  const float* beta  = (const float*)d_in[8];
  const float* rmean = (const float*)d_in[9];
  const float* rvar  = (const float*)d_in[10];
  const float* w2    = (const float*)d_in[11];
  const float* b2    = (const float*)d_in[12];
  float* out = (float*)d_out;
  float* ws  = (float*)d_ws;

  dim3 blk(256);
  k0_prep<<<dim3(313), blk, 0, stream>>>(w1, woff, wd, w2, gamma, beta, rmean, rvar, ws);
  k1_pw1<<<dim3(NBLK), blk, 0, stream>>>(x, ws + OFF_W1T, b1, ws + OFF_FEAT);
  k2_off<<<dim3(NBLK), blk, 0, stream>>>(ws + OFF_FEAT, ws + OFF_WOFFT, boff, ws + OFF_OFFS);
  k3_deform<<<dim3(NBLK), blk, 0, stream>>>(ws + OFF_FEAT, ws + OFF_OFFS, ws + OFF_WDT,
                                            bd, ws + OFF_BNS, ws + OFF_BNB, ws + OFF_V);
  k4_pw2<<<dim3(NBLK), blk, 0, stream>>>(x, ws + OFF_V, ws + OFF_W2T, b2, out);
}

// Round 3
// 381.183 us; speedup vs baseline: 1.5929x; 1.1516x over previous
//
#include <hip/hip_runtime.h>
#include <math.h>

#define H 96
#define W 96
#define HW 9216
#define B 8
#define CIN 256
#define CM 64
#define NPOS (B*HW)   /* 73728 */
#define NBLK (NPOS/64) /* 1152 */

/* workspace layout (float offsets) — 41.4 MiB total */
#define OFF_W1T   0         /* 16384  : w1t[c*64+o]            */
#define OFF_WOFFT 16384     /* 10368  : wofft[c*162+o*9+k]     */
#define OFF_WDT   26752     /* 36864  : wdt2[(k*64+c)*64+o]    */
#define OFF_W2T   63616     /* 16384  : w2t[c*256+o]           */
#define OFF_BNS   80000     /* 64     */
#define OFF_BNB   80064     /* 64     */
#define OFF_FEAT  81920     /* 4718592: feat[b][c][hw]; dead after k2, reused as V */
#define OFF_OFFS  4800512   /* 1327104: offs[b][18][hw]        */
#define OFF_FCL   6127616   /* 4718592: fcl[b][hw][64] channels-last */
#define OFF_V     OFF_FEAT

__global__ __launch_bounds__(256) void k0_prep(
    const float* __restrict__ w1, const float* __restrict__ woff,
    const float* __restrict__ wd, const float* __restrict__ w2,
    const float* __restrict__ gamma, const float* __restrict__ beta,
    const float* __restrict__ rmean, const float* __restrict__ rvar,
    float* __restrict__ ws) {
  int i = blockIdx.x * 256 + threadIdx.x;
  if (i < 16384) {                      /* w1 [o][c] -> w1t [c][o] */
    int c = i >> 6, o = i & 63;
    ws[OFF_W1T + i] = w1[o * CIN + c];
  } else if (i < 26752) {               /* woff [o][c][k] -> wofft [c][o*9+k] */
    int j = i - 16384;
    int c = j / 162, r = j - c * 162;
    int o = r / 9, k = r - o * 9;
    ws[OFF_WOFFT + j] = woff[(o * 64 + c) * 9 + k];
  } else if (i < 63616) {               /* wd [o][c][k] -> wdt2 [k][c][o] */
    int j = i - 26752;
    int o = j & 63, kc = j >> 6;
    int k = kc >> 6, c = kc & 63;
    ws[OFF_WDT + j] = wd[(o * 64 + c) * 9 + k];
  } else if (i < 80000) {               /* w2 [o][c] -> w2t [c][o] */
    int j = i - 63616;
    int c = j >> 8, o = j & 255;
    ws[OFF_W2T + j] = w2[o * 64 + c];
  } else if (i < 80064) {               /* BN folding */
    int o = i - 80000;
    float inv = gamma[o] / sqrtf(rvar[o] + 1e-5f);
    ws[OFF_BNS + o] = inv;
    ws[OFF_BNB + o] = beta[o] - rmean[o] * inv;
  }
}

/* pwconv1: emits channel-major feat (for k2) AND channels-last fcl (for k3) */
__global__ __launch_bounds__(256) void k1_pw1(
    const float* __restrict__ x, const float* __restrict__ w1t,
    const float* __restrict__ b1, float* __restrict__ feat,
    float* __restrict__ fcl) {
  __shared__ float xs[64 * 65];
  int t = threadIdx.x;
  int pos = t & 63;
  int qq = __builtin_amdgcn_readfirstlane(t >> 6);
  int gpos0 = blockIdx.x * 64;
  int b = gpos0 / HW, hw0 = gpos0 - b * HW;
  const float* xb = x + b * CIN * HW + hw0;
  float acc[16];
#pragma unroll
  for (int o = 0; o < 16; o++) acc[o] = 0.f;
  for (int c0 = 0; c0 < CIN; c0 += 64) {
#pragma unroll
    for (int cc = 0; cc < 16; cc++) {
      int ci = qq * 16 + cc;
      xs[ci * 65 + pos] = xb[(c0 + ci) * HW + pos];
    }
    __syncthreads();
#pragma unroll 4
    for (int ci = 0; ci < 64; ci++) {
      float xv = xs[ci * 65 + pos];
      const float4* wr = (const float4*)(w1t + (c0 + ci) * CM + qq * 16);
#pragma unroll
      for (int o4 = 0; o4 < 4; o4++) {
        float4 wv = wr[o4];
        acc[4 * o4 + 0] += xv * wv.x;
        acc[4 * o4 + 1] += xv * wv.y;
        acc[4 * o4 + 2] += xv * wv.z;
        acc[4 * o4 + 3] += xv * wv.w;
      }
    }
    __syncthreads();
  }
  float* fb = feat + b * CM * HW + hw0 + pos;
#pragma unroll
  for (int oo = 0; oo < 16; oo++) {
    int o = qq * 16 + oo;
    float r = acc[oo] + b1[o];
    fb[o * HW] = r;
    xs[pos * 65 + o] = r;   /* stage for transpose; (p+o)%32 -> 2-way, free */
  }
  __syncthreads();
  float* fc = fcl + (size_t)gpos0 * 64;
  for (int r = t; r < 4096; r += 256) {
    int p = r >> 6, c = r & 63;
    fc[r] = xs[p * 65 + c];
  }
}

/* offset conv 64->18: input channels split 4-way, LDS partial reduce */
__global__ __launch_bounds__(256) void k2_off(
    const float* __restrict__ feat, const float* __restrict__ wofft,
    const float* __restrict__ boff, float* __restrict__ offs) {
  __shared__ float part[4 * 18 * 64];
  int t = threadIdx.x;
  int pos = t & 63;
  int gg = __builtin_amdgcn_readfirstlane(t >> 6);
  int gpos0 = blockIdx.x * 64;
  int b = gpos0 / HW, hw0 = gpos0 - b * HW;
  int hw = hw0 + pos;
  int i = hw / W, j = hw - i * W;
  int idx9[9];
  float m9[9];
#pragma unroll
  for (int kh = 0; kh < 3; kh++)
#pragma unroll
    for (int kw = 0; kw < 3; kw++) {
      int yy = i + kh - 1, xx = j + kw - 1;
      bool ok = (yy >= 0) && (yy < H) && (xx >= 0) && (xx < W);
      idx9[kh * 3 + kw] = ok ? yy * W + xx : 0;
      m9[kh * 3 + kw] = ok ? 1.f : 0.f;
    }
  const float* fb = feat + b * CM * HW;
  float acc[18];
#pragma unroll
  for (int o = 0; o < 18; o++) acc[o] = 0.f;
  for (int cc = 0; cc < 16; cc++) {
    int c = gg * 16 + cc;
    const float* fc = fb + c * HW;
    float v[9];
#pragma unroll
    for (int k = 0; k < 9; k++) v[k] = fc[idx9[k]] * m9[k];
    const float* wr = wofft + c * 162;
#pragma unroll
    for (int o = 0; o < 18; o++)
#pragma unroll
      for (int k = 0; k < 9; k++)
        acc[o] += v[k] * wr[o * 9 + k];
  }
#pragma unroll
  for (int o = 0; o < 18; o++) part[(gg * 18 + o) * 64 + pos] = acc[o];
  __syncthreads();
  for (int r = t; r < 18 * 64; r += 256) {
    int o = r >> 6, p = r & 63;
    float s = part[o * 64 + p] + part[(18 + o) * 64 + p] +
              part[(36 + o) * 64 + p] + part[(54 + o) * 64 + p] + boff[o];
    offs[b * 18 * HW + o * HW + hw0 + p] = s;
  }
}

/* deformable conv + BN. Sampling via channels-last fcl: one tap = 256B coalesced. */
__global__ __launch_bounds__(256) void k3_deform(
    const float* __restrict__ fcl, const float* __restrict__ offs,
    const float* __restrict__ wdt2, const float* __restrict__ bd,
    const float* __restrict__ bns, const float* __restrict__ bnb,
    float* __restrict__ v) {
  __shared__ float s_lds[64 * 67];   /* [c*67+pos] */
  __shared__ int   ti[4][576];       /* tap index*64, [tap][k*64+pos] */
  __shared__ float tw[4][576];       /* tap weight */
  int t = threadIdx.x;
  int pos = t & 63;
  int qq = __builtin_amdgcn_readfirstlane(t >> 6);
  int gpos0 = blockIdx.x * 64;
  int b = gpos0 / HW, hw0 = gpos0 - b * HW;
  int hw = hw0 + pos;
  int i = hw / W, j = hw - i * W;
  const float* ob = offs + b * 18 * HW + hw;

  /* tap precompute: wave qq handles k = qq, qq+4, ... (lane = pos) */
  for (int k = qq; k < 9; k += 4) {
    float dy = ob[(2 * k + 0) * HW];
    float dx = ob[(2 * k + 1) * HW];
    float py = (float)(i + k / 3 - 1) + dy;
    float px = (float)(j + k % 3 - 1) + dx;
    float y0f = floorf(py), x0f = floorf(px);
    int y0 = (int)y0f, x0 = (int)x0f;
    float fy = py - y0f, fx = px - x0f;
    float w00 = (1.f - fy) * (1.f - fx), w01 = (1.f - fy) * fx;
    float w10 = fy * (1.f - fx), w11 = fy * fx;
    bool vy0 = (y0 >= 0) && (y0 < H), vy1 = (y0 + 1 >= 0) && (y0 + 1 < H);
    bool vx0 = (x0 >= 0) && (x0 < W), vx1 = (x0 + 1 >= 0) && (x0 + 1 < W);
    if (!(vy0 && vx0)) w00 = 0.f;
    if (!(vy0 && vx1)) w01 = 0.f;
    if (!(vy1 && vx0)) w10 = 0.f;
    if (!(vy1 && vx1)) w11 = 0.f;
    int yi0 = min(max(y0, 0), H - 1), yi1 = min(max(y0 + 1, 0), H - 1);
    int xi0 = min(max(x0, 0), W - 1), xi1 = min(max(x0 + 1, 0), W - 1);
    int e = k * 64 + pos;
    ti[0][e] = (yi0 * W + xi0) * 64;  tw[0][e] = w00;
    ti[1][e] = (yi0 * W + xi1) * 64;  tw[1][e] = w01;
    ti[2][e] = (yi1 * W + xi0) * 64;  tw[2][e] = w10;
    ti[3][e] = (yi1 * W + xi1) * 64;  tw[3][e] = w11;
  }
  __syncthreads();

  const float* fb = fcl + (size_t)b * HW * 64 + pos;  /* lane = channel here */
  float acc[16];
#pragma unroll
  for (int o = 0; o < 16; o++) acc[o] = 0.f;
  for (int k = 0; k < 9; k++) {
    /* sampling: wave qq covers pos qq*16..+15; lane = channel, coalesced taps */
#pragma unroll
    for (int pp = 0; pp < 16; pp++) {
      int p2 = qq * 16 + pp;
      int e = k * 64 + p2;
      float s = tw[0][e] * fb[ti[0][e]] + tw[1][e] * fb[ti[1][e]] +
                tw[2][e] * fb[ti[2][e]] + tw[3][e] * fb[ti[3][e]];
      s_lds[pos * 67 + p2] = s;   /* (3c+p)%32 -> 2-way, free */
    }
    __syncthreads();
    const float* wk = wdt2 + k * 64 * 64 + qq * 16;
#pragma unroll 4
    for (int c = 0; c < 64; c++) {
      float s = s_lds[c * 67 + pos];
      const float4* wr = (const float4*)(wk + c * 64);
#pragma unroll
      for (int o4 = 0; o4 < 4; o4++) {
        float4 wv = wr[o4];
        acc[4 * o4 + 0] += s * wv.x;
        acc[4 * o4 + 1] += s * wv.y;
        acc[4 * o4 + 2] += s * wv.z;
        acc[4 * o4 + 3] += s * wv.w;
      }
    }
    __syncthreads();
  }
  float* vb = v + b * CM * HW + hw;
#pragma unroll
  for (int oo = 0; oo < 16; oo++) {
    int o = qq * 16 + oo;
    vb[o * HW] = (acc[oo] + bd[o]) * bns[o] + bnb[o];
  }
}

/* pwconv2 (64->256) + sigmoid gate; v staged once in LDS, 64 out/group */
__global__ __launch_bounds__(256) void k4_pw2(
    const float* __restrict__ x, const float* __restrict__ v,
    const float* __restrict__ w2t, const float* __restrict__ b2,
    float* __restrict__ out) {
  __shared__ float vs[64 * 65];
  int t = threadIdx.x;
  int pos = t & 63;
  int qq = __builtin_amdgcn_readfirstlane(t >> 6);
  int gpos0 = blockIdx.x * 64;
  int b = gpos0 / HW, hw0 = gpos0 - b * HW;
  int hw = hw0 + pos;
  const float* vb = v + b * CM * HW + hw0;
#pragma unroll
  for (int cc = 0; cc < 16; cc++) {
    int ci = qq * 16 + cc;
    vs[ci * 65 + pos] = vb[ci * HW + pos];
  }
  __syncthreads();
  float acc[64];
#pragma unroll
  for (int o = 0; o < 64; o++) acc[o] = 0.f;
#pragma unroll 2
  for (int c = 0; c < CM; c++) {
    float vv = vs[c * 65 + pos];
    const float4* wr = (const float4*)(w2t + c * 256 + qq * 64);
#pragma unroll
    for (int o4 = 0; o4 < 16; o4++) {
      float4 wv = wr[o4];
      acc[4 * o4 + 0] += vv * wv.x;
      acc[4 * o4 + 1] += vv * wv.y;
      acc[4 * o4 + 2] += vv * wv.z;
      acc[4 * o4 + 3] += vv * wv.w;
    }
  }
  const float* xb = x + (b * CIN + qq * 64) * HW + hw;
  float* outb = out + (b * CIN + qq * 64) * HW + hw;
#pragma unroll
  for (int o = 0; o < 64; o++) {
    float val = acc[o] + b2[qq * 64 + o];
    float sg = 1.f / (1.f + __expf(-val));
    outb[o * HW] = xb[o * HW] * sg;
  }
}

extern "C" void kernel_launch(void* const* d_in, const int* in_sizes, int n_in,
                              void* d_out, int out_size, void* d_ws, size_t ws_size,
                              hipStream_t stream) {
  const float* x     = (const float*)d_in[0];
  const float* w1    = (const float*)d_in[1];
  const float* b1    = (const float*)d_in[2];
  const float* woff  = (const float*)d_in[3];
  const float* boff  = (const float*)d_in[4];
  const float* wd    = (const float*)d_in[5];
  const float* bd    = (const float*)d_in[6];
  const float* gamma = (const float*)d_in[7];
  const float* beta  = (const float*)d_in[8];
  const float* rmean = (const float*)d_in[9];
  const float* rvar  = (const float*)d_in[10];
  const float* w2    = (const float*)d_in[11];
  const float* b2    = (const float*)d_in[12];
  float* out = (float*)d_out;
  float* ws  = (float*)d_ws;

  dim3 blk(256);
  k0_prep<<<dim3(313), blk, 0, stream>>>(w1, woff, wd, w2, gamma, beta, rmean, rvar, ws);
  k1_pw1<<<dim3(NBLK), blk, 0, stream>>>(x, ws + OFF_W1T, b1, ws + OFF_FEAT, ws + OFF_FCL);
  k2_off<<<dim3(NBLK), blk, 0, stream>>>(ws + OFF_FEAT, ws + OFF_WOFFT, boff, ws + OFF_OFFS);
  k3_deform<<<dim3(NBLK), blk, 0, stream>>>(ws + OFF_FCL, ws + OFF_OFFS, ws + OFF_WDT,
                                            bd, ws + OFF_BNS, ws + OFF_BNB, ws + OFF_V);
  k4_pw2<<<dim3(NBLK), blk, 0, stream>>>(x, ws + OFF_V, ws + OFF_W2T, b2, out);
}

// Round 4
// 360.039 us; speedup vs baseline: 1.6864x; 1.0587x over previous
//
#include <hip/hip_runtime.h>
#include <math.h>

#define H 96
#define W 96
#define HW 9216
#define B 8
#define CIN 256
#define CM 64
#define NPOS (B*HW)   /* 73728 */
#define NBLK (NPOS/64) /* 1152 = 8 XCDs x 144 */

/* XCD swizzle: round-robin dispatch -> give XCD g a contiguous 144-block
   (= one batch image, 2.25 MB fcl slice, fits 4MB per-XCD L2) region. */
__device__ __forceinline__ int xswiz(int n) { return (n & 7) * 144 + (n >> 3); }

/* workspace layout (float offsets) — 41.4 MiB total */
#define OFF_W1T   0         /* 16384  : w1t[c*64+o]            */
#define OFF_WOFFT 16384     /* 10368  : wofft[c*162+o*9+k]     */
#define OFF_WDT   26752     /* 36864  : wdt2[(k*64+c)*64+o]    */
#define OFF_W2T   63616     /* 16384  : w2t[c*256+o]           */
#define OFF_BNS   80000     /* 64     */
#define OFF_BNB   80064     /* 64     */
#define OFF_FEAT  81920     /* 4718592: feat[b][c][hw]; dead after k2, reused as V */
#define OFF_OFFS  4800512   /* 1327104: offs[b][18][hw]        */
#define OFF_FCL   6127616   /* 4718592: fcl[b][hw][64] channels-last */
#define OFF_V     OFF_FEAT

__global__ __launch_bounds__(256) void k0_prep(
    const float* __restrict__ w1, const float* __restrict__ woff,
    const float* __restrict__ wd, const float* __restrict__ w2,
    const float* __restrict__ gamma, const float* __restrict__ beta,
    const float* __restrict__ rmean, const float* __restrict__ rvar,
    float* __restrict__ ws) {
  int i = blockIdx.x * 256 + threadIdx.x;
  if (i < 16384) {                      /* w1 [o][c] -> w1t [c][o] */
    int c = i >> 6, o = i & 63;
    ws[OFF_W1T + i] = w1[o * CIN + c];
  } else if (i < 26752) {               /* woff [o][c][k] -> wofft [c][o*9+k] */
    int j = i - 16384;
    int c = j / 162, r = j - c * 162;
    int o = r / 9, k = r - o * 9;
    ws[OFF_WOFFT + j] = woff[(o * 64 + c) * 9 + k];
  } else if (i < 63616) {               /* wd [o][c][k] -> wdt2 [k][c][o] */
    int j = i - 26752;
    int o = j & 63, kc = j >> 6;
    int k = kc >> 6, c = kc & 63;
    ws[OFF_WDT + j] = wd[(o * 64 + c) * 9 + k];
  } else if (i < 80000) {               /* w2 [o][c] -> w2t [c][o] */
    int j = i - 63616;
    int c = j >> 8, o = j & 255;
    ws[OFF_W2T + j] = w2[o * 64 + c];
  } else if (i < 80064) {               /* BN folding */
    int o = i - 80000;
    float inv = gamma[o] / sqrtf(rvar[o] + 1e-5f);
    ws[OFF_BNS + o] = inv;
    ws[OFF_BNB + o] = beta[o] - rmean[o] * inv;
  }
}

/* pwconv1: emits channel-major feat (for k2) AND channels-last fcl (for k3) */
__global__ __launch_bounds__(256) void k1_pw1(
    const float* __restrict__ x, const float* __restrict__ w1t,
    const float* __restrict__ b1, float* __restrict__ feat,
    float* __restrict__ fcl) {
  __shared__ float xs[64 * 65];
  int t = threadIdx.x;
  int pos = t & 63;
  int qq = __builtin_amdgcn_readfirstlane(t >> 6);
  int gpos0 = blockIdx.x * 64;
  int b = gpos0 / HW, hw0 = gpos0 - b * HW;
  const float* xb = x + b * CIN * HW + hw0;
  float acc[16];
#pragma unroll
  for (int o = 0; o < 16; o++) acc[o] = 0.f;
  for (int c0 = 0; c0 < CIN; c0 += 64) {
#pragma unroll
    for (int cc = 0; cc < 16; cc++) {
      int ci = qq * 16 + cc;
      xs[ci * 65 + pos] = xb[(c0 + ci) * HW + pos];
    }
    __syncthreads();
#pragma unroll 4
    for (int ci = 0; ci < 64; ci++) {
      float xv = xs[ci * 65 + pos];
      const float4* wr = (const float4*)(w1t + (c0 + ci) * CM + qq * 16);
#pragma unroll
      for (int o4 = 0; o4 < 4; o4++) {
        float4 wv = wr[o4];
        acc[4 * o4 + 0] += xv * wv.x;
        acc[4 * o4 + 1] += xv * wv.y;
        acc[4 * o4 + 2] += xv * wv.z;
        acc[4 * o4 + 3] += xv * wv.w;
      }
    }
    __syncthreads();
  }
  float* fb = feat + b * CM * HW + hw0 + pos;
#pragma unroll
  for (int oo = 0; oo < 16; oo++) {
    int o = qq * 16 + oo;
    float r = acc[oo] + b1[o];
    fb[o * HW] = r;
    xs[pos * 65 + o] = r;   /* stage for transpose */
  }
  __syncthreads();
  float* fc = fcl + (size_t)gpos0 * 64;
  for (int r = t; r < 4096; r += 256) {
    int p = r >> 6, c = r & 63;
    fc[r] = xs[p * 65 + c];
  }
}

/* offset conv 64->18: input channels split 4-way, LDS partial reduce */
__global__ __launch_bounds__(256) void k2_off(
    const float* __restrict__ feat, const float* __restrict__ wofft,
    const float* __restrict__ boff, float* __restrict__ offs) {
  __shared__ float part[4 * 18 * 64];
  int t = threadIdx.x;
  int pos = t & 63;
  int gg = __builtin_amdgcn_readfirstlane(t >> 6);
  int gpos0 = xswiz(blockIdx.x) * 64;
  int b = gpos0 / HW, hw0 = gpos0 - b * HW;
  int hw = hw0 + pos;
  int i = hw / W, j = hw - i * W;
  int idx9[9];
  float m9[9];
#pragma unroll
  for (int kh = 0; kh < 3; kh++)
#pragma unroll
    for (int kw = 0; kw < 3; kw++) {
      int yy = i + kh - 1, xx = j + kw - 1;
      bool ok = (yy >= 0) && (yy < H) && (xx >= 0) && (xx < W);
      idx9[kh * 3 + kw] = ok ? yy * W + xx : 0;
      m9[kh * 3 + kw] = ok ? 1.f : 0.f;
    }
  const float* fb = feat + b * CM * HW;
  float acc[18];
#pragma unroll
  for (int o = 0; o < 18; o++) acc[o] = 0.f;
  for (int cc = 0; cc < 16; cc++) {
    int c = gg * 16 + cc;
    const float* fc = fb + c * HW;
    float v[9];
#pragma unroll
    for (int k = 0; k < 9; k++) v[k] = fc[idx9[k]] * m9[k];
    const float* wr = wofft + c * 162;
#pragma unroll
    for (int o = 0; o < 18; o++)
#pragma unroll
      for (int k = 0; k < 9; k++)
        acc[o] += v[k] * wr[o * 9 + k];
  }
#pragma unroll
  for (int o = 0; o < 18; o++) part[(gg * 18 + o) * 64 + pos] = acc[o];
  __syncthreads();
  for (int r = t; r < 18 * 64; r += 256) {
    int o = r >> 6, p = r & 63;
    float s = part[o * 64 + p] + part[(18 + o) * 64 + p] +
              part[(36 + o) * 64 + p] + part[(54 + o) * 64 + p] + boff[o];
    offs[b * 18 * HW + o * HW + hw0 + p] = s;
  }
}

/* deformable conv + BN. Channels-last sampling + XCD-local spatial region. */
__global__ __launch_bounds__(256) void k3_deform(
    const float* __restrict__ fcl, const float* __restrict__ offs,
    const float* __restrict__ wdt2, const float* __restrict__ bd,
    const float* __restrict__ bns, const float* __restrict__ bnb,
    float* __restrict__ v) {
  __shared__ float s_lds[64 * 67];   /* [c*67+pos] */
  __shared__ int   ti[4][576];       /* tap index*64, [tap][k*64+pos] */
  __shared__ float tw[4][576];       /* tap weight */
  int t = threadIdx.x;
  int pos = t & 63;
  int qq = __builtin_amdgcn_readfirstlane(t >> 6);
  int gpos0 = xswiz(blockIdx.x) * 64;
  int b = gpos0 / HW, hw0 = gpos0 - b * HW;
  int hw = hw0 + pos;
  int i = hw / W, j = hw - i * W;
  const float* ob = offs + b * 18 * HW + hw;

  /* tap precompute: wave qq handles k = qq, qq+4, ... (lane = pos) */
  for (int k = qq; k < 9; k += 4) {
    float dy = ob[(2 * k + 0) * HW];
    float dx = ob[(2 * k + 1) * HW];
    float py = (float)(i + k / 3 - 1) + dy;
    float px = (float)(j + k % 3 - 1) + dx;
    float y0f = floorf(py), x0f = floorf(px);
    int y0 = (int)y0f, x0 = (int)x0f;
    float fy = py - y0f, fx = px - x0f;
    float w00 = (1.f - fy) * (1.f - fx), w01 = (1.f - fy) * fx;
    float w10 = fy * (1.f - fx), w11 = fy * fx;
    bool vy0 = (y0 >= 0) && (y0 < H), vy1 = (y0 + 1 >= 0) && (y0 + 1 < H);
    bool vx0 = (x0 >= 0) && (x0 < W), vx1 = (x0 + 1 >= 0) && (x0 + 1 < W);
    if (!(vy0 && vx0)) w00 = 0.f;
    if (!(vy0 && vx1)) w01 = 0.f;
    if (!(vy1 && vx0)) w10 = 0.f;
    if (!(vy1 && vx1)) w11 = 0.f;
    int yi0 = min(max(y0, 0), H - 1), yi1 = min(max(y0 + 1, 0), H - 1);
    int xi0 = min(max(x0, 0), W - 1), xi1 = min(max(x0 + 1, 0), W - 1);
    int e = k * 64 + pos;
    ti[0][e] = (yi0 * W + xi0) * 64;  tw[0][e] = w00;
    ti[1][e] = (yi0 * W + xi1) * 64;  tw[1][e] = w01;
    ti[2][e] = (yi1 * W + xi0) * 64;  tw[2][e] = w10;
    ti[3][e] = (yi1 * W + xi1) * 64;  tw[3][e] = w11;
  }
  __syncthreads();

  const float* fb = fcl + (size_t)b * HW * 64 + pos;  /* lane = channel here */
  float acc[16];
#pragma unroll
  for (int o = 0; o < 16; o++) acc[o] = 0.f;
  for (int k = 0; k < 9; k++) {
    /* sampling: wave qq covers pos qq*16..+15; lane = channel, coalesced taps */
#pragma unroll
    for (int pp = 0; pp < 16; pp++) {
      int p2 = qq * 16 + pp;
      int e = k * 64 + p2;
      float s = tw[0][e] * fb[ti[0][e]] + tw[1][e] * fb[ti[1][e]] +
                tw[2][e] * fb[ti[2][e]] + tw[3][e] * fb[ti[3][e]];
      s_lds[pos * 67 + p2] = s;
    }
    __syncthreads();
    const float* wk = wdt2 + k * 64 * 64 + qq * 16;
#pragma unroll 4
    for (int c = 0; c < 64; c++) {
      float s = s_lds[c * 67 + pos];
      const float4* wr = (const float4*)(wk + c * 64);
#pragma unroll
      for (int o4 = 0; o4 < 4; o4++) {
        float4 wv = wr[o4];
        acc[4 * o4 + 0] += s * wv.x;
        acc[4 * o4 + 1] += s * wv.y;
        acc[4 * o4 + 2] += s * wv.z;
        acc[4 * o4 + 3] += s * wv.w;
      }
    }
    __syncthreads();
  }
  float* vb = v + b * CM * HW + hw;
#pragma unroll
  for (int oo = 0; oo < 16; oo++) {
    int o = qq * 16 + oo;
    vb[o * HW] = (acc[oo] + bd[o]) * bns[o] + bnb[o];
  }
}

/* pwconv2 (64->256) + sigmoid gate; v staged once in LDS, 64 out/group */
__global__ __launch_bounds__(256) void k4_pw2(
    const float* __restrict__ x, const float* __restrict__ v,
    const float* __restrict__ w2t, const float* __restrict__ b2,
    float* __restrict__ out) {
  __shared__ float vs[64 * 65];
  int t = threadIdx.x;
  int pos = t & 63;
  int qq = __builtin_amdgcn_readfirstlane(t >> 6);
  int gpos0 = blockIdx.x * 64;
  int b = gpos0 / HW, hw0 = gpos0 - b * HW;
  int hw = hw0 + pos;
  const float* vb = v + b * CM * HW + hw0;
#pragma unroll
  for (int cc = 0; cc < 16; cc++) {
    int ci = qq * 16 + cc;
    vs[ci * 65 + pos] = vb[ci * HW + pos];
  }
  __syncthreads();
  float acc[64];
#pragma unroll
  for (int o = 0; o < 64; o++) acc[o] = 0.f;
#pragma unroll 2
  for (int c = 0; c < CM; c++) {
    float vv = vs[c * 65 + pos];
    const float4* wr = (const float4*)(w2t + c * 256 + qq * 64);
#pragma unroll
    for (int o4 = 0; o4 < 16; o4++) {
      float4 wv = wr[o4];
      acc[4 * o4 + 0] += vv * wv.x;
      acc[4 * o4 + 1] += vv * wv.y;
      acc[4 * o4 + 2] += vv * wv.z;
      acc[4 * o4 + 3] += vv * wv.w;
    }
  }
  const float* xb = x + (b * CIN + qq * 64) * HW + hw;
  float* outb = out + (b * CIN + qq * 64) * HW + hw;
#pragma unroll
  for (int o = 0; o < 64; o++) {
    float val = acc[o] + b2[qq * 64 + o];
    float sg = 1.f / (1.f + __expf(-val));
    outb[o * HW] = xb[o * HW] * sg;
  }
}

extern "C" void kernel_launch(void* const* d_in, const int* in_sizes, int n_in,
                              void* d_out, int out_size, void* d_ws, size_t ws_size,
                              hipStream_t stream) {
  const float* x     = (const float*)d_in[0];
  const float* w1    = (const float*)d_in[1];
  const float* b1    = (const float*)d_in[2];
  const float* woff  = (const float*)d_in[3];
  const float* boff  = (const float*)d_in[4];
  const float* wd    = (const float*)d_in[5];
  const float* bd    = (const float*)d_in[6];
  const float* gamma = (const float*)d_in[7];
  const float* beta  = (const float*)d_in[8];
  const float* rmean = (const float*)d_in[9];
  const float* rvar  = (const float*)d_in[10];
  const float* w2    = (const float*)d_in[11];
  const float* b2    = (const float*)d_in[12];
  float* out = (float*)d_out;
  float* ws  = (float*)d_ws;

  dim3 blk(256);
  k0_prep<<<dim3(313), blk, 0, stream>>>(w1, woff, wd, w2, gamma, beta, rmean, rvar, ws);
  k1_pw1<<<dim3(NBLK), blk, 0, stream>>>(x, ws + OFF_W1T, b1, ws + OFF_FEAT, ws + OFF_FCL);
  k2_off<<<dim3(NBLK), blk, 0, stream>>>(ws + OFF_FEAT, ws + OFF_WOFFT, boff, ws + OFF_OFFS);
  k3_deform<<<dim3(NBLK), blk, 0, stream>>>(ws + OFF_FCL, ws + OFF_OFFS, ws + OFF_WDT,
                                            bd, ws + OFF_BNS, ws + OFF_BNB, ws + OFF_V);
  k4_pw2<<<dim3(NBLK), blk, 0, stream>>>(x, ws + OFF_V, ws + OFF_W2T, b2, out);
}

// Round 6
// 296.473 us; speedup vs baseline: 2.0480x; 1.2144x over previous
//
#include <hip/hip_runtime.h>
#include <math.h>

#define H 96
#define W 96
#define HW 9216
#define B 8
#define CIN 256
#define CM 64
#define NPOS (B*HW)    /* 73728 */
#define NBLK (NPOS/64) /* 1152 = 8 XCDs x 144 */

/* XCD swizzle: round-robin dispatch -> XCD g owns one batch image (2.25MB, fits 4MB L2) */
__device__ __forceinline__ int xswiz(int n) { return (n & 7) * 144 + (n >> 3); }

typedef float  f32x4  __attribute__((ext_vector_type(4)));
typedef short  bf16x8 __attribute__((ext_vector_type(8)));

/* workspace layout (float offsets) — 41.2 MiB total */
#define OFF_WOFFT 0         /* 10368 : wofft[c*162+o*9+k] fp32        */
#define OFF_BNS   10368     /* 64    */
#define OFF_BNB   10432     /* 64    */
#define OFF_WDB1  10496     /* 8192 f = 16384 bf16: w1 B-frags [kc8][nt4][lane][8]  */
#define OFF_WDB3  18688     /* 18432 f = 36864 bf16: wd B-frags [kc18][nt4][lane][8] */
#define OFF_WDB2  37120     /* 8192 f = 16384 bf16: w2 B-frags [kc2][nt16][lane][8] */
#define OFF_FEAT  45312     /* 4718592: feat[b][c][hw] (k2 input); dead after k2 */
#define OFF_FCL   4763904   /* 4718592: fcl[b][hw][64] channels-last */
#define OFF_OFFS  9482496   /* 1327104: offs[b][18][hw] */
#define OFF_VCL   OFF_FEAT  /* 4718592: vcl[b][hw][64] — aliases FEAT (dead) */

/* round-to-nearest-even fp32 -> bf16 (bit pattern in low 16) */
__device__ __forceinline__ unsigned bfbits(float f) {
  union { float f; unsigned u; } c;
  c.f = f;
  return (c.u + 0x7FFFu + ((c.u >> 16) & 1u)) >> 16;
}
__device__ __forceinline__ short f2bf(float f) { return (short)bfbits(f); }
__device__ __forceinline__ unsigned pack2(float lo, float hi) {
  return bfbits(lo) | (bfbits(hi) << 16);
}

/* convert 8 consecutive fp32 (LDS) to an MFMA bf16 A-fragment */
__device__ __forceinline__ bf16x8 cvt_frag(const float* p) {
  const float2* q = (const float2*)p;
  float2 a0 = q[0], a1 = q[1], a2 = q[2], a3 = q[3];
  union { unsigned u[4]; bf16x8 v; } r;
  r.u[0] = pack2(a0.x, a0.y);
  r.u[1] = pack2(a1.x, a1.y);
  r.u[2] = pack2(a2.x, a2.y);
  r.u[3] = pack2(a3.x, a3.y);
  return r.v;
}

/* k0: weight reformat. B-frag layout for mfma_f32_16x16x32_bf16:
   B[k][n], n = nt*16 + (lane&15), k = kc*32 + (lane>>4)*8 + j  (j=0..7 contiguous) */
__global__ __launch_bounds__(256) void k0_prep(
    const float* __restrict__ w1, const float* __restrict__ woff,
    const float* __restrict__ wd, const float* __restrict__ w2,
    const float* __restrict__ gamma, const float* __restrict__ beta,
    const float* __restrict__ rmean, const float* __restrict__ rvar,
    float* __restrict__ ws) {
  int i = blockIdx.x * 256 + threadIdx.x;
  if (i < 10368) {                      /* woff [o][c][k] -> wofft [c][o*9+k] */
    int c = i / 162, r = i - c * 162;
    int o = r / 9, k = r - o * 9;
    ws[OFF_WOFFT + i] = woff[(o * 64 + c) * 9 + k];
  } else if (i < 10432) {               /* BN folding */
    int o = i - 10368;
    float inv = gamma[o] / sqrtf(rvar[o] + 1e-5f);
    ws[OFF_BNS + o] = inv;
    ws[OFF_BNB + o] = beta[o] - rmean[o] * inv;
  } else if (i < 26816) {               /* wdb1: K=c(256), N=o(64) from w1[o][c] */
    int j = i - 10432;
    int j8 = j & 7, lane = (j >> 3) & 63, nt = (j >> 9) & 3, kc = j >> 11;
    int n = nt * 16 + (lane & 15);
    int c = kc * 32 + ((lane >> 4) & 3) * 8 + j8;
    ((short*)(ws + OFF_WDB1))[j] = f2bf(w1[n * 256 + c]);
  } else if (i < 63680) {               /* wdb3: K=(kstep*64+c)(576), N=o from wd[o][c][kstep] */
    int j = i - 26816;
    int j8 = j & 7, lane = (j >> 3) & 63, nt = (j >> 9) & 3, kc = j >> 11;
    int n = nt * 16 + (lane & 15);
    int c = (kc & 1) * 32 + ((lane >> 4) & 3) * 8 + j8;
    int ks = kc >> 1;
    ((short*)(ws + OFF_WDB3))[j] = f2bf(wd[(n * 64 + c) * 9 + ks]);
  } else if (i < 80064) {               /* wdb2: K=c(64), N=o(256) from w2[o][c] */
    int j = i - 63680;
    int j8 = j & 7, lane = (j >> 3) & 63, nt = (j >> 9) & 15, kc = j >> 13;
    int n = nt * 16 + (lane & 15);
    int c = kc * 32 + ((lane >> 4) & 3) * 8 + j8;
    ((short*)(ws + OFF_WDB2))[j] = f2bf(w2[n * 64 + c]);
  }
}

/* k1: pwconv1 via MFMA. M=64 pos, N=64 o, K=256. Emits feat [c][hw] + fcl [hw][c]. */
__global__ __launch_bounds__(256) void k1_pw1(
    const float* __restrict__ x, const short* __restrict__ wdb1,
    const float* __restrict__ b1, float* __restrict__ feat,
    float* __restrict__ fcl) {
  __shared__ float sA[64 * 66];
  int t = threadIdx.x;
  int lane = t & 63;
  int qq = __builtin_amdgcn_readfirstlane(t >> 6);
  int quad = lane >> 4, l15 = lane & 15;
  int mrow = qq * 16 + l15;
  int gpos0 = blockIdx.x * 64;
  int b = gpos0 / HW, hw0 = gpos0 - b * HW;
  f32x4 acc[4];
#pragma unroll
  for (int nt = 0; nt < 4; nt++) acc[nt] = (f32x4){0.f, 0.f, 0.f, 0.f};

  for (int c0 = 0; c0 < CIN; c0 += 64) {
    /* wave-private staging: wave qq loads rows [16qq,16qq+16), all 64 c */
#pragma unroll 4
    for (int it = 0; it < 16; it++) {
      int ci = it * 4 + quad;
      int p = qq * 16 + l15;
      sA[p * 66 + ci] = x[(size_t)(b * CIN + c0 + ci) * HW + hw0 + p];
    }
    /* no barrier: MFMA A-rows are wave-private; compiler orders LDS RAW */
#pragma unroll
    for (int ch = 0; ch < 2; ch++) {
      bf16x8 af = cvt_frag(&sA[mrow * 66 + ch * 32 + quad * 8]);
      int kc = (c0 >> 5) + ch;
#pragma unroll
      for (int nt = 0; nt < 4; nt++) {
        bf16x8 bf = ((const bf16x8*)wdb1)[(kc * 4 + nt) * 64 + lane];
        acc[nt] = __builtin_amdgcn_mfma_f32_16x16x32_bf16(af, bf, acc[nt], 0, 0, 0);
      }
    }
  }
  __syncthreads();
  /* D[m=qq*16+quad*4+reg][n=nt*16+l15] + bias -> LDS */
#pragma unroll
  for (int nt = 0; nt < 4; nt++) {
    int o = nt * 16 + l15;
#pragma unroll
    for (int reg = 0; reg < 4; reg++) {
      int m = qq * 16 + quad * 4 + reg;
      sA[m * 66 + o] = acc[nt][reg] + b1[o];
    }
  }
  __syncthreads();
  for (int rr = t; rr < 4096; rr += 256) {
    int o1 = rr >> 6, p1 = rr & 63;
    feat[(size_t)(b * CM + o1) * HW + hw0 + p1] = sA[p1 * 66 + o1];
    int p2 = rr >> 6, o2 = rr & 63;
    fcl[(size_t)(gpos0 + p2) * 64 + o2] = sA[p2 * 66 + o2];
  }
}

/* k2: offset conv 64->18, fp32 (position precision), unchanged structure */
__global__ __launch_bounds__(256) void k2_off(
    const float* __restrict__ feat, const float* __restrict__ wofft,
    const float* __restrict__ boff, float* __restrict__ offs) {
  __shared__ float part[4 * 18 * 64];
  int t = threadIdx.x;
  int pos = t & 63;
  int gg = __builtin_amdgcn_readfirstlane(t >> 6);
  int gpos0 = xswiz(blockIdx.x) * 64;
  int b = gpos0 / HW, hw0 = gpos0 - b * HW;
  int hw = hw0 + pos;
  int i = hw / W, j = hw - i * W;
  int idx9[9];
  float m9[9];
#pragma unroll
  for (int kh = 0; kh < 3; kh++)
#pragma unroll
    for (int kw = 0; kw < 3; kw++) {
      int yy = i + kh - 1, xx = j + kw - 1;
      bool ok = (yy >= 0) && (yy < H) && (xx >= 0) && (xx < W);
      idx9[kh * 3 + kw] = ok ? yy * W + xx : 0;
      m9[kh * 3 + kw] = ok ? 1.f : 0.f;
    }
  const float* fb = feat + (size_t)b * CM * HW;
  float acc[18];
#pragma unroll
  for (int o = 0; o < 18; o++) acc[o] = 0.f;
  for (int cc = 0; cc < 16; cc++) {
    int c = gg * 16 + cc;
    const float* fc = fb + c * HW;
    float v[9];
#pragma unroll
    for (int k = 0; k < 9; k++) v[k] = fc[idx9[k]] * m9[k];
    const float* wr = wofft + c * 162;
#pragma unroll
    for (int o = 0; o < 18; o++)
#pragma unroll
      for (int k = 0; k < 9; k++)
        acc[o] += v[k] * wr[o * 9 + k];
  }
#pragma unroll
  for (int o = 0; o < 18; o++) part[(gg * 18 + o) * 64 + pos] = acc[o];
  __syncthreads();
  for (int r = t; r < 18 * 64; r += 256) {
    int o = r >> 6, p = r & 63;
    float s = part[o * 64 + p] + part[(18 + o) * 64 + p] +
              part[(36 + o) * 64 + p] + part[(54 + o) * 64 + p] + boff[o];
    offs[(size_t)b * 18 * HW + o * HW + hw0 + p] = s;
  }
}

/* k3: deformable conv + BN via MFMA. M=64 pos, N=64 o, K=576 (9 ksteps x 64c).
   Sampling (fp32) wave-private into LDS; per-kstep barrier-free. */
__global__ __launch_bounds__(256) void k3_deform(
    const float* __restrict__ fcl, const float* __restrict__ offs,
    const short* __restrict__ wdb3, const float* __restrict__ bd,
    const float* __restrict__ bns, const float* __restrict__ bnb,
    float* __restrict__ vcl) {
  __shared__ float sA[64 * 66];
  __shared__ int   ti[4][576];
  __shared__ float tw[4][576];
  int t = threadIdx.x;
  int lane = t & 63;
  int qq = __builtin_amdgcn_readfirstlane(t >> 6);
  int quad = lane >> 4, l15 = lane & 15;
  int mrow = qq * 16 + l15;
  int gpos0 = xswiz(blockIdx.x) * 64;
  int b = gpos0 / HW, hw0 = gpos0 - b * HW;
  int hw = hw0 + lane;
  int i = hw / W, j = hw - i * W;
  const float* ob = offs + (size_t)b * 18 * HW + hw;

  /* tap precompute: wave qq handles k = qq, qq+4, ... (lane = pos) */
  for (int k = qq; k < 9; k += 4) {
    float dy = ob[(2 * k + 0) * HW];
    float dx = ob[(2 * k + 1) * HW];
    float py = (float)(i + k / 3 - 1) + dy;
    float px = (float)(j + k % 3 - 1) + dx;
    float y0f = floorf(py), x0f = floorf(px);
    int y0 = (int)y0f, x0 = (int)x0f;
    float fy = py - y0f, fx = px - x0f;
    float w00 = (1.f - fy) * (1.f - fx), w01 = (1.f - fy) * fx;
    float w10 = fy * (1.f - fx), w11 = fy * fx;
    bool vy0 = (y0 >= 0) && (y0 < H), vy1 = (y0 + 1 >= 0) && (y0 + 1 < H);
    bool vx0 = (x0 >= 0) && (x0 < W), vx1 = (x0 + 1 >= 0) && (x0 + 1 < W);
    if (!(vy0 && vx0)) w00 = 0.f;
    if (!(vy0 && vx1)) w01 = 0.f;
    if (!(vy1 && vx0)) w10 = 0.f;
    if (!(vy1 && vx1)) w11 = 0.f;
    int yi0 = min(max(y0, 0), H - 1), yi1 = min(max(y0 + 1, 0), H - 1);
    int xi0 = min(max(x0, 0), W - 1), xi1 = min(max(x0 + 1, 0), W - 1);
    int e = k * 64 + lane;
    ti[0][e] = (yi0 * W + xi0) * 64;  tw[0][e] = w00;
    ti[1][e] = (yi0 * W + xi1) * 64;  tw[1][e] = w01;
    ti[2][e] = (yi1 * W + xi0) * 64;  tw[2][e] = w10;
    ti[3][e] = (yi1 * W + xi1) * 64;  tw[3][e] = w11;
  }
  __syncthreads();

  const float* fb = fcl + (size_t)b * HW * 64 + lane;  /* lane = channel */
  f32x4 acc[4];
#pragma unroll
  for (int nt = 0; nt < 4; nt++) acc[nt] = (f32x4){0.f, 0.f, 0.f, 0.f};

  for (int ks = 0; ks < 9; ks++) {
    /* sampling: wave qq fills its own rows p2 = qq*16+pp (lane = channel, coalesced) */
#pragma unroll 4
    for (int pp = 0; pp < 16; pp++) {
      int p2 = qq * 16 + pp;
      int e = ks * 64 + p2;
      float s = tw[0][e] * fb[ti[0][e]] + tw[1][e] * fb[ti[1][e]] +
                tw[2][e] * fb[ti[2][e]] + tw[3][e] * fb[ti[3][e]];
      sA[p2 * 66 + lane] = s;
    }
    /* no barrier: A-rows wave-private */
#pragma unroll
    for (int ch = 0; ch < 2; ch++) {
      bf16x8 af = cvt_frag(&sA[mrow * 66 + ch * 32 + quad * 8]);
      int kc = ks * 2 + ch;
#pragma unroll
      for (int nt = 0; nt < 4; nt++) {
        bf16x8 bf = ((const bf16x8*)wdb3)[(kc * 4 + nt) * 64 + lane];
        acc[nt] = __builtin_amdgcn_mfma_f32_16x16x32_bf16(af, bf, acc[nt], 0, 0, 0);
      }
    }
  }
  __syncthreads();
  /* epilogue: bias + BN, stage to LDS, write channels-last vcl */
#pragma unroll
  for (int nt = 0; nt < 4; nt++) {
    int o = nt * 16 + l15;
    float sc = bns[o], sb = bnb[o], bb = bd[o];
#pragma unroll
    for (int reg = 0; reg < 4; reg++) {
      int m = qq * 16 + quad * 4 + reg;
      sA[m * 66 + o] = (acc[nt][reg] + bb) * sc + sb;
    }
  }
  __syncthreads();
  for (int rr = t; rr < 4096; rr += 256) {
    int p = rr >> 6, o = rr & 63;
    vcl[(size_t)(gpos0 + p) * 64 + o] = sA[p * 66 + o];
  }
}

/* k4: pwconv2 via MFMA (M=64 pos, N=256 o, K=64) + sigmoid gate */
__global__ __launch_bounds__(256) void k4_pw2(
    const float* __restrict__ x, const float* __restrict__ vcl,
    const short* __restrict__ wdb2, const float* __restrict__ b2,
    float* __restrict__ out) {
  __shared__ float sA[64 * 66];
  int t = threadIdx.x;
  int lane = t & 63;
  int qq = __builtin_amdgcn_readfirstlane(t >> 6);
  int quad = lane >> 4, l15 = lane & 15;
  int mrow = qq * 16 + l15;
  int gpos0 = blockIdx.x * 64;
  int b = gpos0 / HW, hw0 = gpos0 - b * HW;

  /* wave-private staging of A = vcl rows [16qq,16qq+16) */
#pragma unroll 4
  for (int it = 0; it < 16; it++) {
    int p = qq * 16 + it;
    sA[p * 66 + lane] = vcl[(size_t)(gpos0 + p) * 64 + lane];
  }
  bf16x8 af0 = cvt_frag(&sA[mrow * 66 + 0 * 32 + quad * 8]);
  bf16x8 af1 = cvt_frag(&sA[mrow * 66 + 1 * 32 + quad * 8]);

  f32x4 acc[16];
#pragma unroll
  for (int nt = 0; nt < 16; nt++) acc[nt] = (f32x4){0.f, 0.f, 0.f, 0.f};
#pragma unroll
  for (int nt = 0; nt < 16; nt++) {
    bf16x8 bf0 = ((const bf16x8*)wdb2)[(0 * 16 + nt) * 64 + lane];
    bf16x8 bf1 = ((const bf16x8*)wdb2)[(1 * 16 + nt) * 64 + lane];
    acc[nt] = __builtin_amdgcn_mfma_f32_16x16x32_bf16(af0, bf0, acc[nt], 0, 0, 0);
    acc[nt] = __builtin_amdgcn_mfma_f32_16x16x32_bf16(af1, bf1, acc[nt], 0, 0, 0);
  }
  /* epilogue in 4 chunks of 64 out-channels through LDS */
  for (int nc = 0; nc < 4; nc++) {
    __syncthreads();
#pragma unroll
    for (int nt2 = 0; nt2 < 4; nt2++) {
      int nt = nc * 4 + nt2;
      int o1 = nt2 * 16 + l15;
#pragma unroll
      for (int reg = 0; reg < 4; reg++) {
        int m = qq * 16 + quad * 4 + reg;
        sA[m * 66 + o1] = acc[nt][reg] + b2[nc * 64 + nt2 * 16 + l15];
      }
    }
    __syncthreads();
    for (int rr = t; rr < 4096; rr += 256) {
      int o1 = rr >> 6, p = rr & 63;
      int o = nc * 64 + o1;
      float wv = sA[p * 66 + o1];
      float sg = 1.f / (1.f + __expf(-wv));
      size_t gi = ((size_t)b * CIN + o) * HW + hw0 + p;
      out[gi] = x[gi] * sg;
    }
  }
}

extern "C" void kernel_launch(void* const* d_in, const int* in_sizes, int n_in,
                              void* d_out, int out_size, void* d_ws, size_t ws_size,
                              hipStream_t stream) {
  const float* x     = (const float*)d_in[0];
  const float* w1    = (const float*)d_in[1];
  const float* b1    = (const float*)d_in[2];
  const float* woff  = (const float*)d_in[3];
  const float* boff  = (const float*)d_in[4];
  const float* wd    = (const float*)d_in[5];
  const float* bd    = (const float*)d_in[6];
  const float* gamma = (const float*)d_in[7];
  const float* beta  = (const float*)d_in[8];
  const float* rmean = (const float*)d_in[9];
  const float* rvar  = (const float*)d_in[10];
  const float* w2    = (const float*)d_in[11];
  const float* b2    = (const float*)d_in[12];
  float* out = (float*)d_out;
  float* ws  = (float*)d_ws;

  dim3 blk(256);
  k0_prep<<<dim3(313), blk, 0, stream>>>(w1, woff, wd, w2, gamma, beta, rmean, rvar, ws);
  k1_pw1<<<dim3(NBLK), blk, 0, stream>>>(x, (const short*)(ws + OFF_WDB1), b1,
                                         ws + OFF_FEAT, ws + OFF_FCL);
  k2_off<<<dim3(NBLK), blk, 0, stream>>>(ws + OFF_FEAT, ws + OFF_WOFFT, boff, ws + OFF_OFFS);
  k3_deform<<<dim3(NBLK), blk, 0, stream>>>(ws + OFF_FCL, ws + OFF_OFFS,
                                            (const short*)(ws + OFF_WDB3), bd,
                                            ws + OFF_BNS, ws + OFF_BNB, ws + OFF_VCL);
  k4_pw2<<<dim3(NBLK), blk, 0, stream>>>(x, ws + OFF_VCL, (const short*)(ws + OFF_WDB2),
                                         b2, out);
}